// Round 4
// baseline (170.870 us; speedup 1.0000x reference)
//
#include <hip/hip_runtime.h>

// QuantLinear: out[8,11008] = x[8,4096] @ W[11008,4096]^T
// packed[i] (int32) holds ONE byte: low nibble = weight 2i, high = weight 2i+1; (q-8)*scale[idx/32].
//
// R4: spill-free low-footprint waves + wide loads + deep grid.
//   Grid: 2752 WGs (split-K=2) x 256 thr = 11008 waves. Wave: 2 rows, one K-half (2048),
//   4 tiles of 512 k; lane owns 8 consecutive k = one dwordx4 of packed per row (1 KiB/wave-instr).
//   Register double-buffer on weights+scales keeps misses outstanding during compute.
//   acc[16] (2 rows x 8 m) -> ~90 VGPR, no AGPR shuffling, high occupancy, zero LDS.
//   Epilogue: 4-step shfl_xor tree + xor16/xor32 adds; lanes 0-15 atomicAdd (out memset to 0).

#define OUT_F 11008
#define IN_F  4096

__device__ __forceinline__ void dequant8(const int4 p, const float s, float w[8]) {
    const float ns = -8.f * s;
    w[0] = fmaf((float)(p.x & 15),        s, ns);
    w[1] = fmaf((float)((p.x >> 4) & 15), s, ns);
    w[2] = fmaf((float)(p.y & 15),        s, ns);
    w[3] = fmaf((float)((p.y >> 4) & 15), s, ns);
    w[4] = fmaf((float)(p.z & 15),        s, ns);
    w[5] = fmaf((float)((p.z >> 4) & 15), s, ns);
    w[6] = fmaf((float)(p.w & 15),        s, ns);
    w[7] = fmaf((float)((p.w >> 4) & 15), s, ns);
}

__global__ __launch_bounds__(256) void qlin_kernel(
    const float* __restrict__ x,
    const int*   __restrict__ packed,
    const float* __restrict__ scales,
    float*       __restrict__ out)
{
    const int tid  = threadIdx.x;
    const int lane = tid & 63;
    const int wave = tid >> 6;
    const int b    = blockIdx.x;            // 0..2751
    const int kh   = (b & 1) * 2048;        // K-half
    const int r0   = (b >> 1) * 8 + wave * 2;  // wave's 2 rows

    const int prow0 = r0 * 2048;            // packed dwords per row
    const int prow1 = prow0 + 2048;
    const int srow0 = r0 * 128;             // scales per row
    const int srow1 = srow0 + 128;

    float acc[16];                          // acc[r*8 + m]
#pragma unroll
    for (int i = 0; i < 16; ++i) acc[i] = 0.f;

    int4  wq0[2], wq1[2];
    float sc0[2], sc1[2];

    // prefetch tile 0 (lane's 8 k sit inside one 32-k scale block: kb%32 in {0,8,16,24})
    {
        const int kb = kh + lane * 8;
        wq0[0] = *(const int4*)(packed + prow0 + (kb >> 1));
        wq1[0] = *(const int4*)(packed + prow1 + (kb >> 1));
        sc0[0] = scales[srow0 + (kb >> 5)];
        sc1[0] = scales[srow1 + (kb >> 5)];
    }

#pragma unroll
    for (int t = 0; t < 4; ++t) {
        const int cur = t & 1, nxt = cur ^ 1;
        const int kb = kh + t * 512 + lane * 8;

        if (t < 3) {                        // issue tile t+1 before consuming tile t
            const int kn = kb + 512;
            wq0[nxt] = *(const int4*)(packed + prow0 + (kn >> 1));
            wq1[nxt] = *(const int4*)(packed + prow1 + (kn >> 1));
            sc0[nxt] = scales[srow0 + (kn >> 5)];
            sc1[nxt] = scales[srow1 + (kn >> 5)];
        }

        float w0[8], w1[8];
        dequant8(wq0[cur], sc0[cur], w0);
        dequant8(wq1[cur], sc1[cur], w1);

#pragma unroll
        for (int m = 0; m < 8; ++m) {
            const float4 xa = *(const float4*)(x + m * IN_F + kb);
            const float4 xb = *(const float4*)(x + m * IN_F + kb + 4);
            float a0 = acc[m], a1 = acc[8 + m];
            a0 = fmaf(w0[0], xa.x, a0); a1 = fmaf(w1[0], xa.x, a1);
            a0 = fmaf(w0[1], xa.y, a0); a1 = fmaf(w1[1], xa.y, a1);
            a0 = fmaf(w0[2], xa.z, a0); a1 = fmaf(w1[2], xa.z, a1);
            a0 = fmaf(w0[3], xa.w, a0); a1 = fmaf(w1[3], xa.w, a1);
            a0 = fmaf(w0[4], xb.x, a0); a1 = fmaf(w1[4], xb.x, a1);
            a0 = fmaf(w0[5], xb.y, a0); a1 = fmaf(w1[5], xb.y, a1);
            a0 = fmaf(w0[6], xb.z, a0); a1 = fmaf(w1[6], xb.z, a1);
            a0 = fmaf(w0[7], xb.w, a0); a1 = fmaf(w1[7], xb.w, a1);
            acc[m] = a0; acc[8 + m] = a1;
        }
    }

    // ---- merge tree over 16 values: after 4 steps lane l's acc[0] = subgroup partial
    //      for index l&15; xor-16/32 adds make it the full wave sum ----
#pragma unroll
    for (int s = 0; s < 4; ++s) {
        const int bit = (lane >> s) & 1;
        const int n = 8 >> s;
#pragma unroll
        for (int j = 0; j < n; ++j) {
            const float u = bit ? acc[2 * j + 1] : acc[2 * j];
            const float v = bit ? acc[2 * j]     : acc[2 * j + 1];
            acc[j] = u + __shfl_xor(v, 1 << s, 64);
        }
    }
    acc[0] += __shfl_xor(acc[0], 16, 64);
    acc[0] += __shfl_xor(acc[0], 32, 64);

    if (lane < 16) {
        const int r = lane >> 3;            // index l = r*8 + m
        const int m = lane & 7;
        atomicAdd(out + m * OUT_F + r0 + r, acc[0]);
    }
}

extern "C" void kernel_launch(void* const* d_in, const int* in_sizes, int n_in,
                              void* d_out, int out_size, void* d_ws, size_t ws_size,
                              hipStream_t stream) {
    const float* x      = (const float*)d_in[0];
    const int*   packed = (const int*)  d_in[1];
    const float* scales = (const float*)d_in[2];
    float*       out    = (float*)d_out;

    // split-K atomics accumulate into out -> zero it first (async, graph-capturable)
    hipMemsetAsync(out, 0, (size_t)out_size * sizeof(float), stream);

    dim3 grid((OUT_F / 8) * 2), block(256); // 2752 WGs x 4 waves = 11008 waves
    hipLaunchKernelGGL(qlin_kernel, grid, block, 0, stream,
                       x, packed, scales, out);
}

// Round 5
// 141.345 us; speedup vs baseline: 1.2089x; 1.2089x over previous
//
#include <hip/hip_runtime.h>

// QuantLinear: out[8,11008] = x[8,4096] @ W[11008,4096]^T
// packed[i] (int32) holds ONE byte: low nibble = weight 2i, high = weight 2i+1; (q-8)*scale[idx/32].
//
// R5: decouple x from the weight-prefetch vmcnt stream.
//   Key bug in R2-R4: x global loads were issued after weight prefetch loads; vmcnt is an
//   ordered counter, so waiting on x drained the prefetch -> full HBM latency every tile.
//   Fix: stage x in LDS (ds_read = lgkmcnt, separate counter). Weight loads are then the only
//   vmem ops; a distance-2 register ring keeps 2 tiles of weight misses outstanding always.
//
//   Grid: 1376 row-groups x split-K=4 = 5504 WGs x 256 thr (22016 waves, ~21.5 WG/CU queued).
//   WG: 8 rows, one 1024-k quarter; stage x[8][1024] = 32 KB LDS (5 WGs/CU), one barrier.
//   Wave: 2 rows, 4 tiles of 256 k. Lane owns 4 consecutive k:
//     weights: dwordx2 per row per tile (512 B/wave-instr, coalesced)
//     x: ds_read_b128 at lane*16 B -> conflict-free
//   Epilogue: 4-step shfl_xor tree + xor16/32; lanes 0-15 atomicAdd (out memset to 0).

#define OUT_F 11008
#define IN_F  4096

__device__ __forceinline__ void dequant4(const int2 p, const float s, float w[4]) {
    const float ns = -8.f * s;
    w[0] = fmaf((float)(p.x & 15),        s, ns);
    w[1] = fmaf((float)((p.x >> 4) & 15), s, ns);
    w[2] = fmaf((float)(p.y & 15),        s, ns);
    w[3] = fmaf((float)((p.y >> 4) & 15), s, ns);
}

__global__ __launch_bounds__(256) void qlin_kernel(
    const float* __restrict__ x,
    const int*   __restrict__ packed,
    const float* __restrict__ scales,
    float*       __restrict__ out)
{
    const int tid  = threadIdx.x;
    const int lane = tid & 63;
    const int wave = tid >> 6;
    const int b    = blockIdx.x;
    const int q    = b & 3;                 // k-quarter
    const int g    = b >> 2;                // row-group 0..1375
    const int r0   = g * 8 + wave * 2;      // wave's 2 rows
    const int kq   = q * 1024;              // global k base of quarter

    // weight/scale address bases (tile t adds t*128 dwords / t*8 scales)
    const int p0 = r0 * 2048 + (kq >> 1) + lane * 2;
    const int p1 = p0 + 2048;
    const int s0 = r0 * 128 + (kq >> 5) + (lane >> 3);
    const int s1 = s0 + 128;

    // ---- issue weight prefetch for tiles 0,1 FIRST (they ride out the staging phase) ----
    int2  wq0[3], wq1[3];
    float sc0[3], sc1[3];
    wq0[0] = *(const int2*)(packed + p0);
    wq1[0] = *(const int2*)(packed + p1);
    sc0[0] = scales[s0];
    sc1[0] = scales[s1];
    wq0[1] = *(const int2*)(packed + p0 + 128);
    wq1[1] = *(const int2*)(packed + p1 + 128);
    sc0[1] = scales[s0 + 8];
    sc1[1] = scales[s1 + 8];

    // ---- stage x[8][1024] quarter into LDS (32 KB), fully coalesced ----
    __shared__ float xs[8 * 1024];
    {
        const float* xg = x + kq;
#pragma unroll
        for (int i = 0; i < 8; ++i) {
            const int f  = tid + i * 256;        // float4 id 0..2047
            const int m  = f >> 8;
            const int kv = (f & 255) << 2;       // float offset within quarter
            *(float4*)(xs + m * 1024 + kv) = *(const float4*)(xg + m * IN_F + kv);
        }
    }
    __syncthreads();

    float acc[16];                               // acc[r*8 + m]
#pragma unroll
    for (int i = 0; i < 16; ++i) acc[i] = 0.f;

#pragma unroll
    for (int t = 0; t < 4; ++t) {
        // issue tile t+2 into the slot freed at t-1 (distance-2 ring; never drained
        // by x reads because x comes from LDS = lgkmcnt, not vmcnt)
        if (t < 2) {
            const int u = (t + 2) % 3;
            wq0[u] = *(const int2*)(packed + p0 + (t + 2) * 128);
            wq1[u] = *(const int2*)(packed + p1 + (t + 2) * 128);
            sc0[u] = scales[s0 + (t + 2) * 8];
            sc1[u] = scales[s1 + (t + 2) * 8];
        }

        const int c  = t % 3;
        const int kl = t * 256 + lane * 4;       // local k in quarter (lane's 4 k)

        float w0[4], w1[4];
        dequant4(wq0[c], sc0[c], w0);
        dequant4(wq1[c], sc1[c], w1);

#pragma unroll
        for (int m = 0; m < 8; ++m) {
            const float4 xa = *(const float4*)(xs + m * 1024 + kl);  // ds_read_b128, lane*16B
            float a0 = acc[m], a1 = acc[8 + m];
            a0 = fmaf(w0[0], xa.x, a0); a1 = fmaf(w1[0], xa.x, a1);
            a0 = fmaf(w0[1], xa.y, a0); a1 = fmaf(w1[1], xa.y, a1);
            a0 = fmaf(w0[2], xa.z, a0); a1 = fmaf(w1[2], xa.z, a1);
            a0 = fmaf(w0[3], xa.w, a0); a1 = fmaf(w1[3], xa.w, a1);
            acc[m] = a0; acc[8 + m] = a1;
        }
    }

    // ---- merge tree over 16 values: lane l ends with wave-total for index l&15 ----
#pragma unroll
    for (int s = 0; s < 4; ++s) {
        const int bit = (lane >> s) & 1;
        const int n = 8 >> s;
#pragma unroll
        for (int j = 0; j < n; ++j) {
            const float u = bit ? acc[2 * j + 1] : acc[2 * j];
            const float v = bit ? acc[2 * j]     : acc[2 * j + 1];
            acc[j] = u + __shfl_xor(v, 1 << s, 64);
        }
    }
    acc[0] += __shfl_xor(acc[0], 16, 64);
    acc[0] += __shfl_xor(acc[0], 32, 64);

    if (lane < 16) {
        const int r = lane >> 3;                 // index l = r*8 + m
        const int m = lane & 7;
        atomicAdd(out + m * OUT_F + r0 + r, acc[0]);
    }
}

extern "C" void kernel_launch(void* const* d_in, const int* in_sizes, int n_in,
                              void* d_out, int out_size, void* d_ws, size_t ws_size,
                              hipStream_t stream) {
    const float* x      = (const float*)d_in[0];
    const int*   packed = (const int*)  d_in[1];
    const float* scales = (const float*)d_in[2];
    float*       out    = (float*)d_out;

    // split-K atomics accumulate into out -> zero it first (async, graph-capturable)
    hipMemsetAsync(out, 0, (size_t)out_size * sizeof(float), stream);

    dim3 grid((OUT_F / 8) * 4), block(256);      // 5504 WGs x 4 waves
    hipLaunchKernelGGL(qlin_kernel, grid, block, 0, stream,
                       x, packed, scales, out);
}